// Round 7
// baseline (307.340 us; speedup 1.0000x reference)
//
#include <hip/hip_runtime.h>
#include <hip/hip_bf16.h>
#include <math.h>

#define NHEADS 8
#define CHVAL 32
#define SCB 1024
#define WPB 4   // waves (nodes) per block in node_kernel

// Histogram of dst -> cnt.
__global__ void hist_kernel(const int* __restrict__ dst, int* __restrict__ cnt, int E) {
    int e = blockIdx.x * blockDim.x + threadIdx.x;
    if (e < E) atomicAdd(&cnt[dst[e]], 1);
}

// Pass 1: per-block exclusive scan of cnt (in place), block totals -> btot.
__global__ void scan1_kernel(int* __restrict__ cnt, int* __restrict__ btot, int N) {
    __shared__ int sh[SCB];
    int t = threadIdx.x;
    int i = blockIdx.x * SCB + t;
    int v = (i < N) ? cnt[i] : 0;
    sh[t] = v;
    __syncthreads();
    for (int off = 1; off < SCB; off <<= 1) {
        int y = (t >= off) ? sh[t - off] : 0;
        __syncthreads();
        sh[t] += y;
        __syncthreads();
    }
    if (i < N) cnt[i] = sh[t] - v;          // exclusive within block
    if (t == SCB - 1) btot[blockIdx.x] = sh[t];
}

// Pass 2: single small block scans the (<=64) block totals, exclusive, in place.
__global__ void scan2_kernel(int* __restrict__ btot, int nb) {
    __shared__ int sh[64];
    int t = threadIdx.x;
    int v = (t < nb) ? btot[t] : 0;
    sh[t] = v;
    __syncthreads();
    for (int off = 1; off < 64; off <<= 1) {
        int y = (t >= off) ? sh[t - off] : 0;
        __syncthreads();
        sh[t] += y;
        __syncthreads();
    }
    if (t < nb) btot[t] = sh[t] - v;
}

// Pass 3: offs/cursor = local + block offset; offs[N] = E.
__global__ void scan3_kernel(const int* __restrict__ cnt, const int* __restrict__ btot,
                             int* __restrict__ offs, int* __restrict__ cursor,
                             int N, int E) {
    int i = blockIdx.x * blockDim.x + threadIdx.x;
    if (i < N) {
        int o = cnt[i] + btot[i >> 10];
        offs[i] = o;
        cursor[i] = o;
    }
    if (i == 0) offs[N] = E;
}

// Bucket edges by dst into eid[] using cursor.
__global__ void scatter_kernel(const int* __restrict__ dst,
                               int* __restrict__ cursor,
                               int* __restrict__ eid,
                               int E) {
    int e = blockIdx.x * blockDim.x + threadIdx.x;
    if (e < E) {
        int pos = atomicAdd(&cursor[dst[e]], 1);
        eid[pos] = e;
    }
}

// Fully fused: one WAVE per node computes QK^T logits (lane = slot*8+head,
// 8 lanes cooperate per edge -> 512B contiguous key reads), register softmax
// via __shfl_xor, weights in a per-wave LDS slice, then the value gather loop.
// WPB independent waves per block, no s_barrier anywhere.
__global__ void __launch_bounds__(64 * WPB)
node_kernel(const float4* __restrict__ key0,     // [E*8]  float4
            const float4* __restrict__ key1,     // [E*24] float4
            const float4* __restrict__ q0,       // [N*8]  float4
            const float4* __restrict__ q1,       // [N*24] float4
            const float4* __restrict__ value0,   // [E*8]  float4
            const float4* __restrict__ value1,   // [E*24] float4
            const int* __restrict__ offs,        // [N+1]
            const int* __restrict__ eid,         // [E]
            float4* __restrict__ out0,           // [N*8]  float4
            float4* __restrict__ out1,           // [N*24] float4
            int N) {
    __shared__ float w_sh[WPB][64][9];           // padded stride
    __shared__ int   e_sh[WPB][64];

    int wv = threadIdx.x >> 6;
    int t  = threadIdx.x & 63;
    int n  = blockIdx.x * WPB + wv;
    if (n >= N) return;

    int beg = offs[n];
    int deg = offs[n + 1] - beg;

    if (deg == 0) {
        float4 z = {0.f, 0.f, 0.f, 0.f};
        if (t < 8) out0[(size_t)n * 8 + t] = z;
        else if (t < 32) out1[(size_t)n * 24 + (t - 8)] = z;
        return;
    }

    const float SCALE = 0.08838834764831845f;    // 1/sqrt(128)
    int s = t >> 3;                               // edge slot within group of 8
    int h = t & 7;                                // head

    // preload this node's query slice for head h (64B)
    float4 qa  = q0[(size_t)n * 8 + h];
    float4 qb0 = q1[(size_t)n * 24 + 3 * h + 0];
    float4 qb1 = q1[(size_t)n * 24 + 3 * h + 1];
    float4 qb2 = q1[(size_t)n * 24 + 3 * h + 2];

    // logit for edge slot `slot`, head h; also returns edge id
    auto compute_lg = [&](int slot, int& e_out) -> float {
        int e = eid[beg + slot];
        e_out = e;
        float4 ka  = key0[(size_t)e * 8 + h];
        float4 kb0 = key1[(size_t)e * 24 + 3 * h + 0];
        float4 kb1 = key1[(size_t)e * 24 + 3 * h + 1];
        float4 kb2 = key1[(size_t)e * 24 + 3 * h + 2];
        float d = ka.x * qa.x + ka.y * qa.y + ka.z * qa.z + ka.w * qa.w
                + kb0.x * qb0.x + kb0.y * qb0.y + kb0.z * qb0.z + kb0.w * qb0.w
                + kb1.x * qb1.x + kb1.y * qb1.y + kb1.z * qb1.z + kb1.w * qb1.w
                + kb2.x * qb2.x + kb2.y * qb2.y + kb2.z * qb2.z + kb2.w * qb2.w;
        return d * SCALE;
    };

    // chunk-0 logits (slots 0..min(deg,64)) kept in registers
    float lgreg[8];
    float mxl = -INFINITY;
#pragma unroll
    for (int r = 0; r < 8; ++r) {
        int slot = r * 8 + s;
        float lg = -INFINITY;
        if (slot < deg) {
            int e;
            lg = compute_lg(slot, e);
            if (h == 0) e_sh[wv][slot] = e;
        }
        lgreg[r] = lg;
        mxl = fmaxf(mxl, lg);
    }
    // rare tail (deg > 64): fold into running max (recompute later)
    for (int slot = 64 + s; slot < deg; slot += 8) {
        int e;
        mxl = fmaxf(mxl, compute_lg(slot, e));
    }
    mxl = fmaxf(mxl, __shfl_xor(mxl, 8, 64));
    mxl = fmaxf(mxl, __shfl_xor(mxl, 16, 64));
    mxl = fmaxf(mxl, __shfl_xor(mxl, 32, 64));

    // per-head sum of exp
    float sml = 0.0f;
#pragma unroll
    for (int r = 0; r < 8; ++r) sml += __expf(lgreg[r] - mxl);
    for (int slot = 64 + s; slot < deg; slot += 8) {   // rare
        int e;
        sml += __expf(compute_lg(slot, e) - mxl);
    }
    sml += __shfl_xor(sml, 8, 64);
    sml += __shfl_xor(sml, 16, 64);
    sml += __shfl_xor(sml, 32, 64);
    float inv = 1.0f / sml;

    // chunk-0 weights into LDS
#pragma unroll
    for (int r = 0; r < 8; ++r) {
        int slot = r * 8 + s;
        if (slot < deg) w_sh[wv][slot][h] = __expf(lgreg[r] - mxl) * inv;
    }
    __builtin_amdgcn_wave_barrier();   // compiler fence; DS in-order per wave

    // value accumulation: halves own alternate edges; lane's float4 is a
    // single-head slice of value0/value1.
    int half = t >> 5;
    int l = t & 31;
    int myh = (l < 8) ? l : ((l - 8) / 3);
    float4 acc = {0.f, 0.f, 0.f, 0.f};

    int clen0 = min(deg, 64);
    for (int ii = half; ii < clen0; ii += 2) {
        int e = e_sh[wv][ii];
        float w = w_sh[wv][ii][myh];
        float4 v = (l < 8) ? value0[(size_t)e * 8 + l]
                           : value1[(size_t)e * 24 + (l - 8)];
        acc.x += w * v.x;
        acc.y += w * v.y;
        acc.z += w * v.z;
        acc.w += w * v.w;
    }

    // rare tail chunks: recompute weights per chunk, then accumulate
    for (int base = 64; base < deg; base += 64) {
        __builtin_amdgcn_wave_barrier();
        int clen = min(64, deg - base);
        for (int loc = s; loc < clen; loc += 8) {
            int e;
            float lg = compute_lg(base + loc, e);
            if (h == 0) e_sh[wv][loc] = e;
            w_sh[wv][loc][h] = __expf(lg - mxl) * inv;
        }
        __builtin_amdgcn_wave_barrier();
        for (int ii = half; ii < clen; ii += 2) {
            int e = e_sh[wv][ii];
            float w = w_sh[wv][ii][myh];
            float4 v = (l < 8) ? value0[(size_t)e * 8 + l]
                               : value1[(size_t)e * 24 + (l - 8)];
            acc.x += w * v.x;
            acc.y += w * v.y;
            acc.z += w * v.z;
            acc.w += w * v.w;
        }
    }

    // cross-half reduce, lanes 0-31 store
    acc.x += __shfl_xor(acc.x, 32, 64);
    acc.y += __shfl_xor(acc.y, 32, 64);
    acc.z += __shfl_xor(acc.z, 32, 64);
    acc.w += __shfl_xor(acc.w, 32, 64);
    if (t < 8)       out0[(size_t)n * 8 + l] = acc;
    else if (t < 32) out1[(size_t)n * 24 + (l - 8)] = acc;
}

extern "C" void kernel_launch(void* const* d_in, const int* in_sizes, int n_in,
                              void* d_out, int out_size, void* d_ws, size_t ws_size,
                              hipStream_t stream) {
    const float* key0   = (const float*)d_in[0];
    const float* key1   = (const float*)d_in[1];
    const float* value0 = (const float*)d_in[2];
    const float* value1 = (const float*)d_in[3];
    const float* query0 = (const float*)d_in[4];
    const float* query1 = (const float*)d_in[5];
    const int*   dst    = (const int*)d_in[6];

    int E = in_sizes[0] / CHVAL;   // 500000
    int N = in_sizes[4] / CHVAL;   // 50000
    int nb = (N + SCB - 1) / SCB;  // 49

    // workspace layout (4-byte elements)
    int* cnt    = (int*)d_ws;                // N (reused as local-scan)
    int* offs   = cnt + N;                   // N+1
    int* cursor = offs + N + 1;              // N
    int* eid    = cursor + N;                // E
    int* btot   = eid + E;                   // 64

    float* out0 = (float*)d_out;             // N*32
    float* out1 = out0 + (size_t)N * 32;     // N*96

    hipMemsetAsync(cnt, 0, (size_t)N * sizeof(int), stream);

    int blk = 256;
    hist_kernel<<<(E + blk - 1) / blk, blk, 0, stream>>>(dst, cnt, E);

    scan1_kernel<<<nb, SCB, 0, stream>>>(cnt, btot, N);
    scan2_kernel<<<1, 64, 0, stream>>>(btot, nb);
    scan3_kernel<<<(N + blk - 1) / blk, blk, 0, stream>>>(cnt, btot, offs, cursor, N, E);

    scatter_kernel<<<(E + blk - 1) / blk, blk, 0, stream>>>(dst, cursor, eid, E);

    int nnb = (N + WPB - 1) / WPB;
    node_kernel<<<nnb, 64 * WPB, 0, stream>>>(
        (const float4*)key0, (const float4*)key1,
        (const float4*)query0, (const float4*)query1,
        (const float4*)value0, (const float4*)value1,
        offs, eid,
        (float4*)out0, (float4*)out1, N);
}

// Round 10
// 190.015 us; speedup vs baseline: 1.6175x; 1.6175x over previous
//
#include <hip/hip_runtime.h>
#include <hip/hip_bf16.h>
#include <math.h>

#define NHEADS 8
#define CHVAL 32
#define SCB 1024
#define WPB 4   // waves (nodes) per block in node_kernel

// Per (edge,head): 16-feature dot product -> logits. Head 0 also histograms dst.
__global__ void logits_kernel(const float4* __restrict__ key0,   // [E*8] float4
                              const float4* __restrict__ key1,   // [E*24] float4
                              const float4* __restrict__ q0,     // [N*8] float4
                              const float4* __restrict__ q1,     // [N*24] float4
                              const int* __restrict__ dst,
                              float* __restrict__ logits,        // [E*8]
                              int* __restrict__ cnt,             // [N]
                              int EH) {
    int tid = blockIdx.x * blockDim.x + threadIdx.x;
    if (tid >= EH) return;
    int e = tid >> 3;
    int h = tid & 7;
    int n = dst[e];
    int qh = n * 8 + h;

    float4 a = key0[tid];
    float4 qa = q0[qh];
    float dot = a.x * qa.x + a.y * qa.y + a.z * qa.z + a.w * qa.w;
#pragma unroll
    for (int j = 0; j < 3; ++j) {
        float4 b  = key1[tid * 3 + j];
        float4 qb = q1[qh * 3 + j];
        dot += b.x * qb.x + b.y * qb.y + b.z * qb.z + b.w * qb.w;
    }
    logits[tid] = dot * 0.08838834764831845f;  // 1/sqrt(128)
    if (h == 0) atomicAdd(&cnt[n], 1);
}

// Pass 1: per-block exclusive scan of cnt (in place), block totals -> btot.
__global__ void scan1_kernel(int* __restrict__ cnt, int* __restrict__ btot, int N) {
    __shared__ int sh[SCB];
    int t = threadIdx.x;
    int i = blockIdx.x * SCB + t;
    int v = (i < N) ? cnt[i] : 0;
    sh[t] = v;
    __syncthreads();
    for (int off = 1; off < SCB; off <<= 1) {
        int y = (t >= off) ? sh[t - off] : 0;
        __syncthreads();
        sh[t] += y;
        __syncthreads();
    }
    if (i < N) cnt[i] = sh[t] - v;          // exclusive within block
    if (t == SCB - 1) btot[blockIdx.x] = sh[t];
}

// Pass 2: single small block scans the (<=64) block totals, exclusive, in place.
__global__ void scan2_kernel(int* __restrict__ btot, int nb) {
    __shared__ int sh[64];
    int t = threadIdx.x;
    int v = (t < nb) ? btot[t] : 0;
    sh[t] = v;
    __syncthreads();
    for (int off = 1; off < 64; off <<= 1) {
        int y = (t >= off) ? sh[t - off] : 0;
        __syncthreads();
        sh[t] += y;
        __syncthreads();
    }
    if (t < nb) btot[t] = sh[t] - v;
}

// Pass 3: offs/cursor = local + block offset; offs[N] = E.
__global__ void scan3_kernel(const int* __restrict__ cnt, const int* __restrict__ btot,
                             int* __restrict__ offs, int* __restrict__ cursor,
                             int N, int E) {
    int i = blockIdx.x * blockDim.x + threadIdx.x;
    if (i < N) {
        int o = cnt[i] + btot[i >> 10];
        offs[i] = o;
        cursor[i] = o;
    }
    if (i == 0) offs[N] = E;
}

// Bucket edges by dst into eid[] using cursor.
__global__ void scatter_kernel(const int* __restrict__ dst,
                               int* __restrict__ cursor,
                               int* __restrict__ eid,
                               int E) {
    int e = blockIdx.x * blockDim.x + threadIdx.x;
    if (e < E) {
        int pos = atomicAdd(&cursor[dst[e]], 1);
        eid[pos] = e;
    }
}

// One WAVE (64 lanes) per node; WPB waves per block, fully independent
// (disjoint LDS slices, no s_barrier). Lane i owns edge slot i: loads the
// edge's 8 logits as 2x float4, per-head max/sum via register shuffles,
// weights parked in LDS, values accumulated with float4 loads (2 edges in
// flight per wave), cross-half shuffle reduce, coalesced store.
// NOTE: this is the exact Round-6-verified body. Do NOT hand-unroll the
// value loop (R8/R9 regression) and do NOT load offs[n] as int2 (4B align).
__global__ void __launch_bounds__(64 * WPB)
node_kernel(const float* __restrict__ logits,    // [E*8]
            const float4* __restrict__ value0,   // [E*8]  float4
            const float4* __restrict__ value1,   // [E*24] float4
            const int* __restrict__ offs,        // [N+1]
            const int* __restrict__ eid,         // [E]
            float4* __restrict__ out0,           // [N*8]  float4
            float4* __restrict__ out1,           // [N*24] float4
            int N) {
    __shared__ float w_sh[WPB][64][9];           // padded: stride 9 banks

    int wv = threadIdx.x >> 6;
    int t  = threadIdx.x & 63;
    int n  = blockIdx.x * WPB + wv;
    if (n >= N) return;

    int beg = offs[n];
    int deg = offs[n + 1] - beg;

    if (deg == 0) {
        float4 z = {0.f, 0.f, 0.f, 0.f};
        if (t < 8) out0[(size_t)n * 8 + t] = z;
        else if (t < 32) out1[(size_t)n * 24 + (t - 8)] = z;
        return;
    }

    // gather chunk-0 logits: lane i -> edge slot i, 8 heads (32B contiguous)
    int myeid = -1;
    float lg[8];
    if (t < deg) {
        myeid = eid[beg + t];
        const float4* lp = (const float4*)(logits + (size_t)myeid * 8);
        float4 a = lp[0], b = lp[1];
        lg[0] = a.x; lg[1] = a.y; lg[2] = a.z; lg[3] = a.w;
        lg[4] = b.x; lg[5] = b.y; lg[6] = b.z; lg[7] = b.w;
    } else {
#pragma unroll
        for (int k = 0; k < 8; ++k) lg[k] = -INFINITY;
    }

    // per-head max (running over rare extra chunks)
    float mx[8];
#pragma unroll
    for (int k = 0; k < 8; ++k) mx[k] = lg[k];
    for (int base = 64; base < deg; base += 64) {       // rare: deg > 64
        if (base + t < deg) {
            int e = eid[beg + base + t];
            const float4* lp = (const float4*)(logits + (size_t)e * 8);
            float4 a = lp[0], b = lp[1];
            float tt[8] = {a.x, a.y, a.z, a.w, b.x, b.y, b.z, b.w};
#pragma unroll
            for (int k = 0; k < 8; ++k) mx[k] = fmaxf(mx[k], tt[k]);
        }
    }
#pragma unroll
    for (int k = 0; k < 8; ++k)
        for (int off = 32; off; off >>= 1)
            mx[k] = fmaxf(mx[k], __shfl_xor(mx[k], off, 64));

    // per-head sum of exp (exp(-inf - m) = 0 handles inactive lanes)
    float ex0[8], sm[8];
#pragma unroll
    for (int k = 0; k < 8; ++k) { ex0[k] = __expf(lg[k] - mx[k]); sm[k] = ex0[k]; }
    for (int base = 64; base < deg; base += 64) {       // rare
        if (base + t < deg) {
            int e = eid[beg + base + t];
            const float4* lp = (const float4*)(logits + (size_t)e * 8);
            float4 a = lp[0], b = lp[1];
            float tt[8] = {a.x, a.y, a.z, a.w, b.x, b.y, b.z, b.w};
#pragma unroll
            for (int k = 0; k < 8; ++k) sm[k] += __expf(tt[k] - mx[k]);
        }
    }
#pragma unroll
    for (int k = 0; k < 8; ++k)
        for (int off = 32; off; off >>= 1)
            sm[k] += __shfl_xor(sm[k], off, 64);
    float inv[8];
#pragma unroll
    for (int k = 0; k < 8; ++k) inv[k] = 1.0f / sm[k];

    // value accumulation: each 32-lane half owns alternate edges; lane's
    // float4 is a single-head slice (myh) of value0/value1.
    int half = t >> 5;
    int l = t & 31;
    int myh = (l < 8) ? l : ((l - 8) / 3);
    float4 acc = {0.f, 0.f, 0.f, 0.f};

    for (int base = 0; base < deg; base += 64) {
        int clen = min(64, deg - base);
        if (base == 0) {
            if (t < clen) {
#pragma unroll
                for (int k = 0; k < 8; ++k) w_sh[wv][t][k] = ex0[k] * inv[k];
            }
        } else {                                        // rare
            if (base + t < deg) {
                int e = eid[beg + base + t];
                const float4* lp = (const float4*)(logits + (size_t)e * 8);
                float4 a = lp[0], b = lp[1];
                float tt[8] = {a.x, a.y, a.z, a.w, b.x, b.y, b.z, b.w};
#pragma unroll
                for (int k = 0; k < 8; ++k)
                    w_sh[wv][t][k] = __expf(tt[k] - mx[k]) * inv[k];
            }
        }
        __builtin_amdgcn_wave_barrier();  // compiler fence: DS pipe is in-order per wave

        for (int ii = half; ii < clen; ii += 2) {
            int e = (base == 0) ? __shfl(myeid, ii, 64)
                                : eid[beg + base + ii];
            float w = w_sh[wv][ii][myh];
            float4 v = (l < 8) ? value0[(size_t)e * 8 + l]
                               : value1[(size_t)e * 24 + (l - 8)];
            acc.x += w * v.x;
            acc.y += w * v.y;
            acc.z += w * v.z;
            acc.w += w * v.w;
        }
        __builtin_amdgcn_wave_barrier();
    }

    // cross-half reduce, lanes 0-31 store
    acc.x += __shfl_xor(acc.x, 32, 64);
    acc.y += __shfl_xor(acc.y, 32, 64);
    acc.z += __shfl_xor(acc.z, 32, 64);
    acc.w += __shfl_xor(acc.w, 32, 64);
    if (t < 8)       out0[(size_t)n * 8 + l] = acc;
    else if (t < 32) out1[(size_t)n * 24 + (l - 8)] = acc;
}

extern "C" void kernel_launch(void* const* d_in, const int* in_sizes, int n_in,
                              void* d_out, int out_size, void* d_ws, size_t ws_size,
                              hipStream_t stream) {
    const float* key0   = (const float*)d_in[0];
    const float* key1   = (const float*)d_in[1];
    const float* value0 = (const float*)d_in[2];
    const float* value1 = (const float*)d_in[3];
    const float* query0 = (const float*)d_in[4];
    const float* query1 = (const float*)d_in[5];
    const int*   dst    = (const int*)d_in[6];

    int E = in_sizes[0] / CHVAL;   // 500000
    int N = in_sizes[4] / CHVAL;   // 50000
    int EH = E * NHEADS;
    int nb = (N + SCB - 1) / SCB;  // 49

    // workspace layout (4-byte elements)
    float* logits = (float*)d_ws;            // EH
    int*   cnt    = (int*)(logits + EH);     // N (reused as local-scan)
    int*   offs   = cnt + N;                 // N+1
    int*   cursor = offs + N + 1;            // N
    int*   eid    = cursor + N;              // E
    int*   btot   = eid + E;                 // 64

    float* out0 = (float*)d_out;             // N*32
    float* out1 = out0 + (size_t)N * 32;     // N*96

    hipMemsetAsync(cnt, 0, (size_t)N * sizeof(int), stream);

    int blk = 256;
    logits_kernel<<<(EH + blk - 1) / blk, blk, 0, stream>>>(
        (const float4*)key0, (const float4*)key1,
        (const float4*)query0, (const float4*)query1,
        dst, logits, cnt, EH);

    scan1_kernel<<<nb, SCB, 0, stream>>>(cnt, btot, N);
    scan2_kernel<<<1, 64, 0, stream>>>(btot, nb);
    scan3_kernel<<<(N + blk - 1) / blk, blk, 0, stream>>>(cnt, btot, offs, cursor, N, E);

    scatter_kernel<<<(E + blk - 1) / blk, blk, 0, stream>>>(dst, cursor, eid, E);

    int nnb = (N + WPB - 1) / WPB;
    node_kernel<<<nnb, 64 * WPB, 0, stream>>>(logits,
                                              (const float4*)value0,
                                              (const float4*)value1,
                                              offs, eid,
                                              (float4*)out0, (float4*)out1, N);
}